// Round 6
// baseline (500.687 us; speedup 1.0000x reference)
//
#include <hip/hip_runtime.h>
#include <hip/hip_bf16.h>
#include <stdint.h>

#define NNODES 50000
#define NEDGES 800000
#define CH     256
#define NCLS   64
#define DCAP   64     // per-node edge capacity (P(deg>64) ~ 1e-13 for this dataset)

typedef __attribute__((ext_vector_type(8))) short  short8;
typedef __attribute__((ext_vector_type(4))) float  floatx4;

__device__ __forceinline__ float bf2f(unsigned short u) {
    union { unsigned int i; float f; } v; v.i = ((unsigned int)u) << 16; return v.f;
}
__device__ __forceinline__ unsigned short f2bf(float f) {
    union { float f; unsigned int i; } v; v.f = f;
    unsigned int x = v.i;
    return (unsigned short)((x + 0x7fffu + ((x >> 16) & 1u)) >> 16);  // RNE
}

// async 16B global -> LDS (DMA; tracked by vmcnt, drained by __syncthreads)
__device__ __forceinline__ void gl_lds16(const void* g, void* l) {
    __builtin_amdgcn_global_load_lds(
        (const __attribute__((address_space(1))) unsigned int*)g,
        (__attribute__((address_space(3))) unsigned int*)l, 16, 0, 0);
}

// ------- fused setup: zero cnt + transpose-convert weights + x -> bf16 cast -------
__global__ void k_setup(const float* __restrict__ W0, const float* __restrict__ W1,
                        const float* __restrict__ Wl, const float* __restrict__ x,
                        unsigned short* __restrict__ w0t, unsigned short* __restrict__ w1t,
                        unsigned short* __restrict__ wlt, unsigned short* __restrict__ xbf,
                        int* __restrict__ cnt) {
    int i = blockIdx.x * 256 + threadIdx.x;
    if (i < 65536) {
        int r = i >> 8, c = i & 255;
        w0t[c * 256 + r] = f2bf(W0[i]);
    } else if (i < 131072) {
        int j = i - 65536;
        int r = j >> 8, c = j & 255;
        w1t[c * 256 + r] = f2bf(W1[j]);
    } else if (i < 147456) {
        int j = i - 131072;
        int r = j >> 6, c = j & 63;       // Wl is [256,64]
        wlt[c * 256 + r] = f2bf(Wl[j]);
    } else if (i < 147456 + NNODES) {
        cnt[i - 147456] = 0;
    } else {
        int j = i - (147456 + NNODES);    // 8-elem chunk of x
        if (j < NNODES * CH / 8) {
            const float4* xp = (const float4*)(x + (size_t)j * 8);
            float4 v0 = xp[0], v1 = xp[1];
            ushort4 o0, o1;
            o0.x = f2bf(v0.x); o0.y = f2bf(v0.y); o0.z = f2bf(v0.z); o0.w = f2bf(v0.w);
            o1.x = f2bf(v1.x); o1.y = f2bf(v1.y); o1.z = f2bf(v1.z); o1.w = f2bf(v1.w);
            *(ushort4*)(xbf + (size_t)j * 8)     = o0;
            *(ushort4*)(xbf + (size_t)j * 8 + 4) = o1;
        }
    }
}

// ------- one-pass bucket-CSR: append src into fixed-stride slots of dst -------
__global__ void k_scatter(const int* __restrict__ dst, const int* __restrict__ src,
                          int* __restrict__ cnt, int* __restrict__ esrc) {
    int e = blockIdx.x * 256 + threadIdx.x;
    if (e < NEDGES) {
        int d = dst[e];
        if ((unsigned)d < NNODES) {
            int p = atomicAdd(&cnt[d], 1);
            if (p < DCAP) esrc[(size_t)d * DCAP + p] = src[e];
        }
    }
}

// ---------------- GEMM: 64(M) x BN(N) per block, B staged via global_load_lds ------------
// A fragments: direct global->reg; B: [2][BN][32] linear LDS dbuf via 16B DMA.
// HEL>0 fuses el/er epilogue (needs BN==N==CH).
template<int BN, bool AF32, bool OUTF32, int HEL>
__global__ __launch_bounds__(256) void k_gemml(const void* __restrict__ Av,
                                               const unsigned short* __restrict__ BT,
                                               const float* __restrict__ bias,
                                               float* __restrict__ Cf,
                                               unsigned short* __restrict__ Cb,
                                               int M, int N,
                                               const float* __restrict__ al,
                                               const float* __restrict__ ar,
                                               float* __restrict__ el,
                                               float* __restrict__ er) {
    constexpr int NT  = BN / 16;
    constexpr int RPW = BN / 4;      // B rows staged per wave per K-step
    constexpr int P   = RPW / 16;    // gl_lds16 instructions per wave per K-step
    __shared__ unsigned short Bs[2][BN][32];
    const int t  = threadIdx.x;
    const int w  = t >> 6, l = t & 63;
    const int lm = l & 15, lg = l >> 4;        // fragment row / k-group
    const int m0 = blockIdx.x * 64;
    const int arow = m0 + w * 16 + lm;
    const unsigned short* Ab = (const unsigned short*)Av;
    const float*          Af = (const float*)Av;

    const int srow  = w * RPW + (l >> 2);
    const int sslot = (l & 3) * 8;             // elems (16 B)

    floatx4 acc[NT];
#pragma unroll
    for (int nt = 0; nt < NT; ++nt) acc[nt] = (floatx4)0.0f;

#pragma unroll
    for (int p = 0; p < P; ++p)
        gl_lds16(BT + (size_t)(srow + p * 16) * 256 + sslot,
                 &Bs[0][w * RPW + p * 16][0]);
    short8 af0 = (short8)0, af1 = (short8)0;
    if (arow < M) {
        if (AF32) {
            const float* ap = Af + (size_t)arow * 256 + lg * 8;
            float4 v0 = *(const float4*)(ap), v1 = *(const float4*)(ap + 4);
            af0[0] = (short)f2bf(v0.x); af0[1] = (short)f2bf(v0.y);
            af0[2] = (short)f2bf(v0.z); af0[3] = (short)f2bf(v0.w);
            af0[4] = (short)f2bf(v1.x); af0[5] = (short)f2bf(v1.y);
            af0[6] = (short)f2bf(v1.z); af0[7] = (short)f2bf(v1.w);
        } else {
            af0 = *(const short8*)(Ab + (size_t)arow * 256 + lg * 8);
        }
    }
    __syncthreads();

    int cur = 0;
    for (int ks = 0; ks < 8; ++ks) {
        if (ks < 7) {
            int k1 = (ks + 1) * 32;
#pragma unroll
            for (int p = 0; p < P; ++p)
                gl_lds16(BT + (size_t)(srow + p * 16) * 256 + k1 + sslot,
                         &Bs[cur ^ 1][w * RPW + p * 16][0]);
            af1 = (short8)0;
            if (arow < M) {
                if (AF32) {
                    const float* ap = Af + (size_t)arow * 256 + k1 + lg * 8;
                    float4 v0 = *(const float4*)(ap), v1 = *(const float4*)(ap + 4);
                    af1[0] = (short)f2bf(v0.x); af1[1] = (short)f2bf(v0.y);
                    af1[2] = (short)f2bf(v0.z); af1[3] = (short)f2bf(v0.w);
                    af1[4] = (short)f2bf(v1.x); af1[5] = (short)f2bf(v1.y);
                    af1[6] = (short)f2bf(v1.z); af1[7] = (short)f2bf(v1.w);
                } else {
                    af1 = *(const short8*)(Ab + (size_t)arow * 256 + k1 + lg * 8);
                }
            }
        }
#pragma unroll
        for (int nt = 0; nt < NT; ++nt) {
            short8 bf = *(const short8*)&Bs[cur][nt * 16 + lm][lg * 8];
            acc[nt] = __builtin_amdgcn_mfma_f32_16x16x32_bf16(af0, bf, acc[nt], 0, 0, 0);
        }
        af0 = af1;
        if (ks < 7) { __syncthreads(); cur ^= 1; }
    }

    float alv[HEL > 0 ? NT : 1], arv[HEL > 0 ? NT : 1];
    if (HEL > 0) {
#pragma unroll
        for (int nt = 0; nt < NT; ++nt) {
            alv[nt] = al[nt * 16 + lm];
            arv[nt] = ar[nt * 16 + lm];
        }
    }

#pragma unroll
    for (int j = 0; j < 4; ++j) {
        int row = m0 + w * 16 + (l >> 4) * 4 + j;
        if (row < M) {
#pragma unroll
            for (int nt = 0; nt < NT; ++nt) {
                int gcol = nt * 16 + lm;
                float v = acc[nt][j];
                if (bias) v += bias[gcol];
                if (OUTF32) Cf[(size_t)row * N + gcol] = v;
                else        Cb[(size_t)row * N + gcol] = f2bf(v);
            }
            if (HEL > 0) {
#pragma unroll
                for (int h = 0; h < HEL; ++h) {
                    float sl = 0.f, sr = 0.f;
#pragma unroll
                    for (int q = 0; q < NT / HEL; ++q) {
                        int nt = h * (NT / HEL) + q;
                        float v = acc[nt][j];
                        sl += v * alv[nt];
                        sr += v * arv[nt];
                    }
#pragma unroll
                    for (int mm = 1; mm < 16; mm <<= 1) {
                        sl += __shfl_xor(sl, mm, 64);
                        sr += __shfl_xor(sr, mm, 64);
                    }
                    if (lm == 0) {
                        el[(size_t)row * HEL + h] = sl;
                        er[(size_t)row * HEL + h] = sr;
                    }
                }
            }
        }
    }
}

// ---------------- aggregation: inline softmax weight + scalar gather-FMA ----------------
// Bucket CSR: node n's edges at esrc[n*DCAP .. n*DCAP+deg). CLS fuses the final
// classifier: lane l computes logits[n,l] from the wave's LDS-staged h-row.
template<int H, bool ELU, bool RESID, bool CLS>
__global__ __launch_bounds__(256) void k_agg4(
        const unsigned short* __restrict__ ft,
        const float* __restrict__ el, const float* __restrict__ er,
        const int* __restrict__ cnt,
        const int* __restrict__ esrc,
        const unsigned short* __restrict__ resid16,
        const float* __restrict__ bias,
        unsigned short* __restrict__ out_bf,
        float* __restrict__ out_f,
        const unsigned short* __restrict__ wlt,
        const float* __restrict__ bl,
        float* __restrict__ logits) {
    __shared__ float sm[4][CH];
    int w = threadIdx.x >> 6;
    int n = blockIdx.x * 4 + w;
    int l = threadIdx.x & 63;
    int c = 4 * l;
    int st = n * DCAP;
    int dg = __builtin_amdgcn_readfirstlane(cnt[n]);
    if (dg > DCAP) dg = DCAP;
    if (dg < 0) dg = 0;
    float a0 = 0.f, a1 = 0.f, a2 = 0.f, a3 = 0.f, wsum = 0.f;
    const unsigned short* ftc = ft + c;

    if (H == 1) {
        float ern = er[n];
        for (int i = 0; i < dg; i += 64) {
            int idx = i + l;
            int sv = 0; float wv = 0.f;
            if (idx < dg) {
                sv = esrc[st + idx];
                float xv = el[sv] + ern;
                xv = (xv > 0.f) ? xv : 0.2f * xv;
                xv = fminf(xv, 60.f);
                wv = __expf(xv);
            }
            wsum += wv;
            int jmax = dg - i; if (jmax > 64) jmax = 64;
            int j = 0;
            for (; j + 4 <= jmax; j += 4) {
                int s0 = __builtin_amdgcn_readlane(sv, j + 0);
                int s1 = __builtin_amdgcn_readlane(sv, j + 1);
                int s2 = __builtin_amdgcn_readlane(sv, j + 2);
                int s3 = __builtin_amdgcn_readlane(sv, j + 3);
                float w0 = __int_as_float(__builtin_amdgcn_readlane(__float_as_int(wv), j + 0));
                float w1 = __int_as_float(__builtin_amdgcn_readlane(__float_as_int(wv), j + 1));
                float w2 = __int_as_float(__builtin_amdgcn_readlane(__float_as_int(wv), j + 2));
                float w3 = __int_as_float(__builtin_amdgcn_readlane(__float_as_int(wv), j + 3));
                ushort4 f0 = *(const ushort4*)(ftc + (size_t)s0 * CH);
                ushort4 f1 = *(const ushort4*)(ftc + (size_t)s1 * CH);
                ushort4 f2 = *(const ushort4*)(ftc + (size_t)s2 * CH);
                ushort4 f3 = *(const ushort4*)(ftc + (size_t)s3 * CH);
                a0 += w0 * bf2f(f0.x) + w1 * bf2f(f1.x) + w2 * bf2f(f2.x) + w3 * bf2f(f3.x);
                a1 += w0 * bf2f(f0.y) + w1 * bf2f(f1.y) + w2 * bf2f(f2.y) + w3 * bf2f(f3.y);
                a2 += w0 * bf2f(f0.z) + w1 * bf2f(f1.z) + w2 * bf2f(f2.z) + w3 * bf2f(f3.z);
                a3 += w0 * bf2f(f0.w) + w1 * bf2f(f1.w) + w2 * bf2f(f2.w) + w3 * bf2f(f3.w);
            }
            for (; j < jmax; ++j) {
                int s0 = __builtin_amdgcn_readlane(sv, j);
                float w0 = __int_as_float(__builtin_amdgcn_readlane(__float_as_int(wv), j));
                ushort4 f0 = *(const ushort4*)(ftc + (size_t)s0 * CH);
                a0 += w0 * bf2f(f0.x); a1 += w0 * bf2f(f0.y);
                a2 += w0 * bf2f(f0.z); a3 += w0 * bf2f(f0.w);
            }
        }
#pragma unroll
        for (int m = 1; m < 64; m <<= 1) wsum += __shfl_xor(wsum, m, 64);
    } else {
        int head = l & 3, slot = l >> 2;       // phase-1 role of this lane
        int h = l >> 4;                        // phase-2 head (c / 64)
        float ern = er[n * 4 + head];
        for (int i = 0; i < dg; i += 16) {
            int idx = i + slot;
            int sv = 0; float wv = 0.f;
            if (idx < dg) {
                sv = esrc[st + idx];
                float xv = el[sv * 4 + head] + ern;
                xv = (xv > 0.f) ? xv : 0.2f * xv;
                xv = fminf(xv, 60.f);
                wv = __expf(xv);
            }
            wsum += wv;
            int jmax = dg - i; if (jmax > 16) jmax = 16;
            int j = 0;
            for (; j + 4 <= jmax; j += 4) {
                int s0 = __builtin_amdgcn_readlane(sv, 4 * (j + 0));
                int s1 = __builtin_amdgcn_readlane(sv, 4 * (j + 1));
                int s2 = __builtin_amdgcn_readlane(sv, 4 * (j + 2));
                int s3 = __builtin_amdgcn_readlane(sv, 4 * (j + 3));
                float w0 = __shfl(wv, 4 * (j + 0) + h, 64);
                float w1 = __shfl(wv, 4 * (j + 1) + h, 64);
                float w2 = __shfl(wv, 4 * (j + 2) + h, 64);
                float w3 = __shfl(wv, 4 * (j + 3) + h, 64);
                ushort4 f0 = *(const ushort4*)(ftc + (size_t)s0 * CH);
                ushort4 f1 = *(const ushort4*)(ftc + (size_t)s1 * CH);
                ushort4 f2 = *(const ushort4*)(ftc + (size_t)s2 * CH);
                ushort4 f3 = *(const ushort4*)(ftc + (size_t)s3 * CH);
                a0 += w0 * bf2f(f0.x) + w1 * bf2f(f1.x) + w2 * bf2f(f2.x) + w3 * bf2f(f3.x);
                a1 += w0 * bf2f(f0.y) + w1 * bf2f(f1.y) + w2 * bf2f(f2.y) + w3 * bf2f(f3.y);
                a2 += w0 * bf2f(f0.z) + w1 * bf2f(f1.z) + w2 * bf2f(f2.z) + w3 * bf2f(f3.z);
                a3 += w0 * bf2f(f0.w) + w1 * bf2f(f1.w) + w2 * bf2f(f2.w) + w3 * bf2f(f3.w);
            }
            for (; j < jmax; ++j) {
                int s0 = __builtin_amdgcn_readlane(sv, 4 * j);
                float w0 = __shfl(wv, 4 * j + h, 64);
                ushort4 f0 = *(const ushort4*)(ftc + (size_t)s0 * CH);
                a0 += w0 * bf2f(f0.x); a1 += w0 * bf2f(f0.y);
                a2 += w0 * bf2f(f0.z); a3 += w0 * bf2f(f0.w);
            }
        }
#pragma unroll
        for (int m = 4; m < 64; m <<= 1) wsum += __shfl_xor(wsum, m, 64);
        wsum = __shfl(wsum, l >> 4, 64);
    }
    float inv = (wsum > 1e-30f) ? 1.0f / wsum : 0.0f;
    a0 *= inv; a1 *= inv; a2 *= inv; a3 *= inv;
    if (RESID) {
        ushort4 r = *(const ushort4*)(resid16 + (size_t)n * CH + c);
        a0 += bf2f(r.x); a1 += bf2f(r.y); a2 += bf2f(r.z); a3 += bf2f(r.w);
    }
    {
        float4 b = *(const float4*)(bias + c);
        a0 += b.x; a1 += b.y; a2 += b.z; a3 += b.w;
    }
    if (ELU) {
        a0 = (a0 > 0.f) ? a0 : __expf(a0) - 1.f;
        a1 = (a1 > 0.f) ? a1 : __expf(a1) - 1.f;
        a2 = (a2 > 0.f) ? a2 : __expf(a2) - 1.f;
        a3 = (a3 > 0.f) ? a3 : __expf(a3) - 1.f;
    }
    if (out_bf) {
        ushort4 ov; ov.x = f2bf(a0); ov.y = f2bf(a1); ov.z = f2bf(a2); ov.w = f2bf(a3);
        *(ushort4*)(out_bf + (size_t)n * CH + c) = ov;
    }
    if (out_f) {
        *(float4*)(out_f + (size_t)n * CH + c) = make_float4(a0, a1, a2, a3);
    }
    if (CLS) {
        // stage this wave's h-row to LDS; lane l computes class l.
        // Same-wave RAW through LDS: compiler inserts the lgkmcnt wait.
        *(float4*)&sm[w][c] = make_float4(a0, a1, a2, a3);
        const unsigned short* wr = wlt + (size_t)l * CH;
        float dot = 0.f;
#pragma unroll
        for (int cc = 0; cc < CH; cc += 8) {
            float4 s0 = *(const float4*)&sm[w][cc];
            float4 s1 = *(const float4*)&sm[w][cc + 4];
            short8 wv = *(const short8*)(wr + cc);
            dot += s0.x * bf2f((unsigned short)wv[0]) + s0.y * bf2f((unsigned short)wv[1])
                 + s0.z * bf2f((unsigned short)wv[2]) + s0.w * bf2f((unsigned short)wv[3])
                 + s1.x * bf2f((unsigned short)wv[4]) + s1.y * bf2f((unsigned short)wv[5])
                 + s1.z * bf2f((unsigned short)wv[6]) + s1.w * bf2f((unsigned short)wv[7]);
        }
        logits[(size_t)n * NCLS + l] = dot + bl[l];
    }
}

// ---------------- launch ----------------

extern "C" void kernel_launch(void* const* d_in, const int* in_sizes, int n_in,
                              void* d_out, int out_size, void* d_ws, size_t ws_size,
                              hipStream_t stream) {
    const float* x   = (const float*)d_in[0];
    const int*   src = (const int*)d_in[1];
    const int*   dst = (const int*)d_in[2];
    const float* W0  = (const float*)d_in[3];
    const float* al0 = (const float*)d_in[4];
    const float* ar0 = (const float*)d_in[5];
    const float* b0  = (const float*)d_in[6];
    const float* W1  = (const float*)d_in[7];
    const float* al1 = (const float*)d_in[8];
    const float* ar1 = (const float*)d_in[9];
    const float* b1  = (const float*)d_in[10];
    const float* Wl  = (const float*)d_in[11];
    const float* bl  = (const float*)d_in[12];

    float* out_logits = (float*)d_out;
    float* out_h      = out_logits + (size_t)NNODES * NCLS;

    // xbf (25.6 MB) lives in the out_h region: dead after GEMM-0, long before agg<1> writes out_h
    unsigned short* xbf = (unsigned short*)out_h;

    // ws: ft 25.6 + h0bf 25.6 + esrc 12.8 + weights ~0.3 + small arrays (~66.5 MB total)
    char* ws = (char*)d_ws;
    size_t o = 0;
    auto alloc = [&](size_t b) { char* p = ws + o; o += (b + 255) & ~(size_t)255; return p; };
    unsigned short* ft   = (unsigned short*)alloc((size_t)NNODES * CH * 2);
    unsigned short* h0bf = (unsigned short*)alloc((size_t)NNODES * CH * 2);
    int*            esrc = (int*)alloc((size_t)NNODES * DCAP * 4);
    unsigned short* w0t  = (unsigned short*)alloc(256 * 256 * 2);
    unsigned short* w1t  = (unsigned short*)alloc(256 * 256 * 2);
    unsigned short* wlt  = (unsigned short*)alloc(64 * 256 * 2);
    int*            cnt  = (int*)alloc((size_t)NNODES * 4);
    float*          el0  = (float*)alloc((size_t)NNODES * 4 * 4);
    float*          er0  = (float*)alloc((size_t)NNODES * 4 * 4);
    float*          el1  = (float*)alloc((size_t)NNODES * 4);
    float*          er1  = (float*)alloc((size_t)NNODES * 4);

    // ---- setup (weights + xcast + cnt zero) + one-pass bucket CSR ----
    int setup_items = 147456 + NNODES + NNODES * CH / 8;
    k_setup<<<(setup_items + 255) / 256, 256, 0, stream>>>(W0, W1, Wl, x,
                                                           w0t, w1t, wlt, xbf, cnt);
    k_scatter<<<(NEDGES + 255) / 256, 256, 0, stream>>>(dst, src, cnt, esrc);

    int gm = (NNODES + 63) / 64;  // 782
    // ---- layer 0 ----
    k_gemml<256, false, false, 4><<<gm, 256, 0, stream>>>(
        xbf, w0t, nullptr, nullptr, ft, NNODES, CH, al0, ar0, el0, er0);
    k_agg4<4, true, false, false><<<NNODES / 4, 256, 0, stream>>>(
        ft, el0, er0, cnt, esrc, nullptr, b0, h0bf, nullptr, nullptr, nullptr, nullptr);
    // ---- layer 1 (+ fused classifier in epilogue) ----
    k_gemml<256, false, false, 1><<<gm, 256, 0, stream>>>(
        h0bf, w1t, nullptr, nullptr, ft, NNODES, CH, al1, ar1, el1, er1);
    k_agg4<1, false, true, true><<<NNODES / 4, 256, 0, stream>>>(
        ft, el1, er1, cnt, esrc, h0bf, b1, nullptr, out_h, wlt, bl, out_logits);
}

// Round 7
// 355.185 us; speedup vs baseline: 1.4097x; 1.4097x over previous
//
#include <hip/hip_runtime.h>
#include <hip/hip_bf16.h>
#include <stdint.h>

#define NNODES 50000
#define NEDGES 800000
#define CH     256
#define NCLS   64
#define DCAP   64     // per-node edge capacity (P(deg>64) ~ 1e-13 for this dataset)

typedef __attribute__((ext_vector_type(8))) short  short8;
typedef __attribute__((ext_vector_type(4))) float  floatx4;

__device__ __forceinline__ float bf2f(unsigned short u) {
    union { unsigned int i; float f; } v; v.i = ((unsigned int)u) << 16; return v.f;
}
__device__ __forceinline__ unsigned short f2bf(float f) {
    union { float f; unsigned int i; } v; v.f = f;
    unsigned int x = v.i;
    return (unsigned short)((x + 0x7fffu + ((x >> 16) & 1u)) >> 16);  // RNE
}

// async 16B global -> LDS (DMA; tracked by vmcnt, drained by __syncthreads)
__device__ __forceinline__ void gl_lds16(const void* g, void* l) {
    __builtin_amdgcn_global_load_lds(
        (const __attribute__((address_space(1))) unsigned int*)g,
        (__attribute__((address_space(3))) unsigned int*)l, 16, 0, 0);
}

// ------- fused setup: zero cnt + transpose-convert weights + x -> bf16 cast -------
__global__ void k_setup(const float* __restrict__ W0, const float* __restrict__ W1,
                        const float* __restrict__ Wl, const float* __restrict__ x,
                        unsigned short* __restrict__ w0t, unsigned short* __restrict__ w1t,
                        unsigned short* __restrict__ wlt, unsigned short* __restrict__ xbf,
                        int* __restrict__ cnt) {
    int i = blockIdx.x * 256 + threadIdx.x;
    if (i < 65536) {
        int r = i >> 8, c = i & 255;
        w0t[c * 256 + r] = f2bf(W0[i]);
    } else if (i < 131072) {
        int j = i - 65536;
        int r = j >> 8, c = j & 255;
        w1t[c * 256 + r] = f2bf(W1[j]);
    } else if (i < 147456) {
        int j = i - 131072;
        int r = j >> 6, c = j & 63;       // Wl is [256,64]
        wlt[c * 256 + r] = f2bf(Wl[j]);
    } else if (i < 147456 + NNODES) {
        cnt[i - 147456] = 0;
    } else {
        int j = i - (147456 + NNODES);    // 8-elem chunk of x
        if (j < NNODES * CH / 8) {
            const float4* xp = (const float4*)(x + (size_t)j * 8);
            float4 v0 = xp[0], v1 = xp[1];
            ushort4 o0, o1;
            o0.x = f2bf(v0.x); o0.y = f2bf(v0.y); o0.z = f2bf(v0.z); o0.w = f2bf(v0.w);
            o1.x = f2bf(v1.x); o1.y = f2bf(v1.y); o1.z = f2bf(v1.z); o1.w = f2bf(v1.w);
            *(ushort4*)(xbf + (size_t)j * 8)     = o0;
            *(ushort4*)(xbf + (size_t)j * 8 + 4) = o1;
        }
    }
}

// ------- one-pass bucket-CSR: append src into fixed-stride slots of dst -------
__global__ void k_scatter(const int* __restrict__ dst, const int* __restrict__ src,
                          int* __restrict__ cnt, int* __restrict__ esrc) {
    int e = blockIdx.x * 256 + threadIdx.x;
    if (e < NEDGES) {
        int d = dst[e];
        if ((unsigned)d < NNODES) {
            int p = atomicAdd(&cnt[d], 1);
            if (p < DCAP) esrc[(size_t)d * DCAP + p] = src[e];
        }
    }
}

// ---------------- GEMM: 64(M) x BN(N) per block, B staged via global_load_lds ------------
// A fragments: direct global->reg; B: [2][BN][32] linear LDS dbuf via 16B DMA.
// HEL>0 fuses el/er epilogue (needs BN==N==CH).
template<int BN, bool AF32, bool OUTF32, int HEL>
__global__ __launch_bounds__(256) void k_gemml(const void* __restrict__ Av,
                                               const unsigned short* __restrict__ BT,
                                               const float* __restrict__ bias,
                                               float* __restrict__ Cf,
                                               unsigned short* __restrict__ Cb,
                                               int M, int N,
                                               const float* __restrict__ al,
                                               const float* __restrict__ ar,
                                               float* __restrict__ el,
                                               float* __restrict__ er) {
    constexpr int NT  = BN / 16;
    constexpr int RPW = BN / 4;      // B rows staged per wave per K-step
    constexpr int P   = RPW / 16;    // gl_lds16 instructions per wave per K-step
    __shared__ unsigned short Bs[2][BN][32];
    const int t  = threadIdx.x;
    const int w  = t >> 6, l = t & 63;
    const int lm = l & 15, lg = l >> 4;        // fragment row / k-group
    const int m0 = blockIdx.x * 64;
    const int arow = m0 + w * 16 + lm;
    const unsigned short* Ab = (const unsigned short*)Av;
    const float*          Af = (const float*)Av;

    const int srow  = w * RPW + (l >> 2);
    const int sslot = (l & 3) * 8;             // elems (16 B)

    floatx4 acc[NT];
#pragma unroll
    for (int nt = 0; nt < NT; ++nt) acc[nt] = (floatx4)0.0f;

#pragma unroll
    for (int p = 0; p < P; ++p)
        gl_lds16(BT + (size_t)(srow + p * 16) * 256 + sslot,
                 &Bs[0][w * RPW + p * 16][0]);
    short8 af0 = (short8)0, af1 = (short8)0;
    if (arow < M) {
        if (AF32) {
            const float* ap = Af + (size_t)arow * 256 + lg * 8;
            float4 v0 = *(const float4*)(ap), v1 = *(const float4*)(ap + 4);
            af0[0] = (short)f2bf(v0.x); af0[1] = (short)f2bf(v0.y);
            af0[2] = (short)f2bf(v0.z); af0[3] = (short)f2bf(v0.w);
            af0[4] = (short)f2bf(v1.x); af0[5] = (short)f2bf(v1.y);
            af0[6] = (short)f2bf(v1.z); af0[7] = (short)f2bf(v1.w);
        } else {
            af0 = *(const short8*)(Ab + (size_t)arow * 256 + lg * 8);
        }
    }
    __syncthreads();

    int cur = 0;
    for (int ks = 0; ks < 8; ++ks) {
        if (ks < 7) {
            int k1 = (ks + 1) * 32;
#pragma unroll
            for (int p = 0; p < P; ++p)
                gl_lds16(BT + (size_t)(srow + p * 16) * 256 + k1 + sslot,
                         &Bs[cur ^ 1][w * RPW + p * 16][0]);
            af1 = (short8)0;
            if (arow < M) {
                if (AF32) {
                    const float* ap = Af + (size_t)arow * 256 + k1 + lg * 8;
                    float4 v0 = *(const float4*)(ap), v1 = *(const float4*)(ap + 4);
                    af1[0] = (short)f2bf(v0.x); af1[1] = (short)f2bf(v0.y);
                    af1[2] = (short)f2bf(v0.z); af1[3] = (short)f2bf(v0.w);
                    af1[4] = (short)f2bf(v1.x); af1[5] = (short)f2bf(v1.y);
                    af1[6] = (short)f2bf(v1.z); af1[7] = (short)f2bf(v1.w);
                } else {
                    af1 = *(const short8*)(Ab + (size_t)arow * 256 + k1 + lg * 8);
                }
            }
        }
#pragma unroll
        for (int nt = 0; nt < NT; ++nt) {
            short8 bf = *(const short8*)&Bs[cur][nt * 16 + lm][lg * 8];
            acc[nt] = __builtin_amdgcn_mfma_f32_16x16x32_bf16(af0, bf, acc[nt], 0, 0, 0);
        }
        af0 = af1;
        if (ks < 7) { __syncthreads(); cur ^= 1; }
    }

    float alv[HEL > 0 ? NT : 1], arv[HEL > 0 ? NT : 1];
    if (HEL > 0) {
#pragma unroll
        for (int nt = 0; nt < NT; ++nt) {
            alv[nt] = al[nt * 16 + lm];
            arv[nt] = ar[nt * 16 + lm];
        }
    }

#pragma unroll
    for (int j = 0; j < 4; ++j) {
        int row = m0 + w * 16 + (l >> 4) * 4 + j;
        if (row < M) {
#pragma unroll
            for (int nt = 0; nt < NT; ++nt) {
                int gcol = nt * 16 + lm;
                float v = acc[nt][j];
                if (bias) v += bias[gcol];
                if (OUTF32) Cf[(size_t)row * N + gcol] = v;
                else        Cb[(size_t)row * N + gcol] = f2bf(v);
            }
            if (HEL > 0) {
#pragma unroll
                for (int h = 0; h < HEL; ++h) {
                    float sl = 0.f, sr = 0.f;
#pragma unroll
                    for (int q = 0; q < NT / HEL; ++q) {
                        int nt = h * (NT / HEL) + q;
                        float v = acc[nt][j];
                        sl += v * alv[nt];
                        sr += v * arv[nt];
                    }
#pragma unroll
                    for (int mm = 1; mm < 16; mm <<= 1) {
                        sl += __shfl_xor(sl, mm, 64);
                        sr += __shfl_xor(sr, mm, 64);
                    }
                    if (lm == 0) {
                        el[(size_t)row * HEL + h] = sl;
                        er[(size_t)row * HEL + h] = sr;
                    }
                }
            }
        }
    }
}

// ---------------- aggregation: inline softmax weight + scalar gather-FMA ----------------
// Bucket CSR: node n's edges at esrc[n*DCAP .. n*DCAP+deg). No LDS.
template<int H, bool ELU, bool RESID>
__global__ __launch_bounds__(256) void k_agg5(
        const unsigned short* __restrict__ ft,
        const float* __restrict__ el, const float* __restrict__ er,
        const int* __restrict__ cnt,
        const int* __restrict__ esrc,
        const unsigned short* __restrict__ resid16,
        const float* __restrict__ bias,
        unsigned short* __restrict__ out_bf,
        float* __restrict__ out_f) {
    int w = threadIdx.x >> 6;
    int n = blockIdx.x * 4 + w;
    int l = threadIdx.x & 63;
    int c = 4 * l;
    int st = n * DCAP;
    int dg = __builtin_amdgcn_readfirstlane(cnt[n]);
    if (dg > DCAP) dg = DCAP;
    if (dg < 0) dg = 0;
    float a0 = 0.f, a1 = 0.f, a2 = 0.f, a3 = 0.f, wsum = 0.f;
    const unsigned short* ftc = ft + c;

    if (H == 1) {
        float ern = er[n];
        for (int i = 0; i < dg; i += 64) {
            int idx = i + l;
            int sv = 0; float wv = 0.f;
            if (idx < dg) {
                sv = esrc[st + idx];
                float xv = el[sv] + ern;
                xv = (xv > 0.f) ? xv : 0.2f * xv;
                xv = fminf(xv, 60.f);
                wv = __expf(xv);
            }
            wsum += wv;
            int jmax = dg - i; if (jmax > 64) jmax = 64;
            int j = 0;
            for (; j + 4 <= jmax; j += 4) {
                int s0 = __builtin_amdgcn_readlane(sv, j + 0);
                int s1 = __builtin_amdgcn_readlane(sv, j + 1);
                int s2 = __builtin_amdgcn_readlane(sv, j + 2);
                int s3 = __builtin_amdgcn_readlane(sv, j + 3);
                float w0 = __int_as_float(__builtin_amdgcn_readlane(__float_as_int(wv), j + 0));
                float w1 = __int_as_float(__builtin_amdgcn_readlane(__float_as_int(wv), j + 1));
                float w2 = __int_as_float(__builtin_amdgcn_readlane(__float_as_int(wv), j + 2));
                float w3 = __int_as_float(__builtin_amdgcn_readlane(__float_as_int(wv), j + 3));
                ushort4 f0 = *(const ushort4*)(ftc + (size_t)s0 * CH);
                ushort4 f1 = *(const ushort4*)(ftc + (size_t)s1 * CH);
                ushort4 f2 = *(const ushort4*)(ftc + (size_t)s2 * CH);
                ushort4 f3 = *(const ushort4*)(ftc + (size_t)s3 * CH);
                a0 += w0 * bf2f(f0.x) + w1 * bf2f(f1.x) + w2 * bf2f(f2.x) + w3 * bf2f(f3.x);
                a1 += w0 * bf2f(f0.y) + w1 * bf2f(f1.y) + w2 * bf2f(f2.y) + w3 * bf2f(f3.y);
                a2 += w0 * bf2f(f0.z) + w1 * bf2f(f1.z) + w2 * bf2f(f2.z) + w3 * bf2f(f3.z);
                a3 += w0 * bf2f(f0.w) + w1 * bf2f(f1.w) + w2 * bf2f(f2.w) + w3 * bf2f(f3.w);
            }
            for (; j < jmax; ++j) {
                int s0 = __builtin_amdgcn_readlane(sv, j);
                float w0 = __int_as_float(__builtin_amdgcn_readlane(__float_as_int(wv), j));
                ushort4 f0 = *(const ushort4*)(ftc + (size_t)s0 * CH);
                a0 += w0 * bf2f(f0.x); a1 += w0 * bf2f(f0.y);
                a2 += w0 * bf2f(f0.z); a3 += w0 * bf2f(f0.w);
            }
        }
#pragma unroll
        for (int m = 1; m < 64; m <<= 1) wsum += __shfl_xor(wsum, m, 64);
    } else {
        int head = l & 3, slot = l >> 2;       // phase-1 role of this lane
        int h = l >> 4;                        // phase-2 head (c / 64)
        float ern = er[n * 4 + head];
        for (int i = 0; i < dg; i += 16) {
            int idx = i + slot;
            int sv = 0; float wv = 0.f;
            if (idx < dg) {
                sv = esrc[st + idx];
                float xv = el[sv * 4 + head] + ern;
                xv = (xv > 0.f) ? xv : 0.2f * xv;
                xv = fminf(xv, 60.f);
                wv = __expf(xv);
            }
            wsum += wv;
            int jmax = dg - i; if (jmax > 16) jmax = 16;
            int j = 0;
            for (; j + 4 <= jmax; j += 4) {
                int s0 = __builtin_amdgcn_readlane(sv, 4 * (j + 0));
                int s1 = __builtin_amdgcn_readlane(sv, 4 * (j + 1));
                int s2 = __builtin_amdgcn_readlane(sv, 4 * (j + 2));
                int s3 = __builtin_amdgcn_readlane(sv, 4 * (j + 3));
                float w0 = __shfl(wv, 4 * (j + 0) + h, 64);
                float w1 = __shfl(wv, 4 * (j + 1) + h, 64);
                float w2 = __shfl(wv, 4 * (j + 2) + h, 64);
                float w3 = __shfl(wv, 4 * (j + 3) + h, 64);
                ushort4 f0 = *(const ushort4*)(ftc + (size_t)s0 * CH);
                ushort4 f1 = *(const ushort4*)(ftc + (size_t)s1 * CH);
                ushort4 f2 = *(const ushort4*)(ftc + (size_t)s2 * CH);
                ushort4 f3 = *(const ushort4*)(ftc + (size_t)s3 * CH);
                a0 += w0 * bf2f(f0.x) + w1 * bf2f(f1.x) + w2 * bf2f(f2.x) + w3 * bf2f(f3.x);
                a1 += w0 * bf2f(f0.y) + w1 * bf2f(f1.y) + w2 * bf2f(f2.y) + w3 * bf2f(f3.y);
                a2 += w0 * bf2f(f0.z) + w1 * bf2f(f1.z) + w2 * bf2f(f2.z) + w3 * bf2f(f3.z);
                a3 += w0 * bf2f(f0.w) + w1 * bf2f(f1.w) + w2 * bf2f(f2.w) + w3 * bf2f(f3.w);
            }
            for (; j < jmax; ++j) {
                int s0 = __builtin_amdgcn_readlane(sv, 4 * j);
                float w0 = __shfl(wv, 4 * j + h, 64);
                ushort4 f0 = *(const ushort4*)(ftc + (size_t)s0 * CH);
                a0 += w0 * bf2f(f0.x); a1 += w0 * bf2f(f0.y);
                a2 += w0 * bf2f(f0.z); a3 += w0 * bf2f(f0.w);
            }
        }
#pragma unroll
        for (int m = 4; m < 64; m <<= 1) wsum += __shfl_xor(wsum, m, 64);
        wsum = __shfl(wsum, l >> 4, 64);
    }
    float inv = (wsum > 1e-30f) ? 1.0f / wsum : 0.0f;
    a0 *= inv; a1 *= inv; a2 *= inv; a3 *= inv;
    if (RESID) {
        ushort4 r = *(const ushort4*)(resid16 + (size_t)n * CH + c);
        a0 += bf2f(r.x); a1 += bf2f(r.y); a2 += bf2f(r.z); a3 += bf2f(r.w);
    }
    {
        float4 b = *(const float4*)(bias + c);
        a0 += b.x; a1 += b.y; a2 += b.z; a3 += b.w;
    }
    if (ELU) {
        a0 = (a0 > 0.f) ? a0 : __expf(a0) - 1.f;
        a1 = (a1 > 0.f) ? a1 : __expf(a1) - 1.f;
        a2 = (a2 > 0.f) ? a2 : __expf(a2) - 1.f;
        a3 = (a3 > 0.f) ? a3 : __expf(a3) - 1.f;
    }
    if (out_bf) {
        ushort4 ov; ov.x = f2bf(a0); ov.y = f2bf(a1); ov.z = f2bf(a2); ov.w = f2bf(a3);
        *(ushort4*)(out_bf + (size_t)n * CH + c) = ov;
    }
    if (out_f) {
        *(float4*)(out_f + (size_t)n * CH + c) = make_float4(a0, a1, a2, a3);
    }
}

// ---------------- launch ----------------

extern "C" void kernel_launch(void* const* d_in, const int* in_sizes, int n_in,
                              void* d_out, int out_size, void* d_ws, size_t ws_size,
                              hipStream_t stream) {
    const float* x   = (const float*)d_in[0];
    const int*   src = (const int*)d_in[1];
    const int*   dst = (const int*)d_in[2];
    const float* W0  = (const float*)d_in[3];
    const float* al0 = (const float*)d_in[4];
    const float* ar0 = (const float*)d_in[5];
    const float* b0  = (const float*)d_in[6];
    const float* W1  = (const float*)d_in[7];
    const float* al1 = (const float*)d_in[8];
    const float* ar1 = (const float*)d_in[9];
    const float* b1  = (const float*)d_in[10];
    const float* Wl  = (const float*)d_in[11];
    const float* bl  = (const float*)d_in[12];

    float* out_logits = (float*)d_out;
    float* out_h      = out_logits + (size_t)NNODES * NCLS;

    // xbf (25.6 MB) lives in the out_h region: dead after GEMM-0, long before agg<1> writes out_h
    unsigned short* xbf = (unsigned short*)out_h;

    // ws: ft 25.6 + h0bf 25.6 + esrc 12.8 + weights ~0.3 + small arrays (~66.5 MB total)
    char* ws = (char*)d_ws;
    size_t o = 0;
    auto alloc = [&](size_t b) { char* p = ws + o; o += (b + 255) & ~(size_t)255; return p; };
    unsigned short* ft   = (unsigned short*)alloc((size_t)NNODES * CH * 2);
    unsigned short* h0bf = (unsigned short*)alloc((size_t)NNODES * CH * 2);
    int*            esrc = (int*)alloc((size_t)NNODES * DCAP * 4);
    unsigned short* w0t  = (unsigned short*)alloc(256 * 256 * 2);
    unsigned short* w1t  = (unsigned short*)alloc(256 * 256 * 2);
    unsigned short* wlt  = (unsigned short*)alloc(64 * 256 * 2);
    int*            cnt  = (int*)alloc((size_t)NNODES * 4);
    float*          el0  = (float*)alloc((size_t)NNODES * 4 * 4);
    float*          er0  = (float*)alloc((size_t)NNODES * 4 * 4);
    float*          el1  = (float*)alloc((size_t)NNODES * 4);
    float*          er1  = (float*)alloc((size_t)NNODES * 4);

    // ---- setup (weights + xcast + cnt zero) + one-pass bucket CSR ----
    int setup_items = 147456 + NNODES + NNODES * CH / 8;
    k_setup<<<(setup_items + 255) / 256, 256, 0, stream>>>(W0, W1, Wl, x,
                                                           w0t, w1t, wlt, xbf, cnt);
    k_scatter<<<(NEDGES + 255) / 256, 256, 0, stream>>>(dst, src, cnt, esrc);

    int gm = (NNODES + 63) / 64;  // 782
    // ---- layer 0 ----
    k_gemml<256, false, false, 4><<<gm, 256, 0, stream>>>(
        xbf, w0t, nullptr, nullptr, ft, NNODES, CH, al0, ar0, el0, er0);
    k_agg5<4, true, false><<<NNODES / 4, 256, 0, stream>>>(
        ft, el0, er0, cnt, esrc, nullptr, b0, h0bf, nullptr);
    // ---- layer 1 ----
    k_gemml<256, false, false, 1><<<gm, 256, 0, stream>>>(
        h0bf, w1t, nullptr, nullptr, ft, NNODES, CH, al1, ar1, el1, er1);
    k_agg5<1, false, true><<<NNODES / 4, 256, 0, stream>>>(
        ft, el1, er1, cnt, esrc, h0bf, b1, nullptr, out_h);
    // ---- classifier (reads out_h f32) ----
    k_gemml<64, true, true, 0><<<gm, 256, 0, stream>>>(
        out_h, wlt, bl, out_logits, nullptr, NNODES, NCLS,
        nullptr, nullptr, nullptr, nullptr);
}

// Round 8
// 344.956 us; speedup vs baseline: 1.4515x; 1.0297x over previous
//
#include <hip/hip_runtime.h>
#include <hip/hip_bf16.h>
#include <stdint.h>

#define NNODES 50000
#define NEDGES 800000
#define CH     256
#define NCLS   64
#define DCAP   64     // per-node edge capacity (P(deg>64) ~ 1e-13 for this dataset)
#define RB     224    // rows per GEMM block (7 waves x 32)

typedef __attribute__((ext_vector_type(8))) short  short8;
typedef __attribute__((ext_vector_type(4))) float  floatx4;

__device__ __forceinline__ float bf2f(unsigned short u) {
    union { unsigned int i; float f; } v; v.i = ((unsigned int)u) << 16; return v.f;
}
__device__ __forceinline__ unsigned short f2bf(float f) {
    union { float f; unsigned int i; } v; v.f = f;
    unsigned int x = v.i;
    return (unsigned short)((x + 0x7fffu + ((x >> 16) & 1u)) >> 16);  // RNE
}

// async 16B global -> LDS (DMA; vmcnt-tracked, drained by __syncthreads)
__device__ __forceinline__ void gl_lds16(const void* g, void* l) {
    __builtin_amdgcn_global_load_lds(
        (const __attribute__((address_space(1))) unsigned int*)g,
        (__attribute__((address_space(3))) unsigned int*)l, 16, 0, 0);
}

// ------- fused setup: zero cnt + transpose-convert weights + x -> bf16 cast -------
__global__ void k_setup(const float* __restrict__ W0, const float* __restrict__ W1,
                        const float* __restrict__ Wl, const float* __restrict__ x,
                        unsigned short* __restrict__ w0t, unsigned short* __restrict__ w1t,
                        unsigned short* __restrict__ wlt, unsigned short* __restrict__ xbf,
                        int* __restrict__ cnt) {
    int i = blockIdx.x * 256 + threadIdx.x;
    if (i < 65536) {
        int r = i >> 8, c = i & 255;
        w0t[c * 256 + r] = f2bf(W0[i]);
    } else if (i < 131072) {
        int j = i - 65536;
        int r = j >> 8, c = j & 255;
        w1t[c * 256 + r] = f2bf(W1[j]);
    } else if (i < 147456) {
        int j = i - 131072;
        int r = j >> 6, c = j & 63;       // Wl is [256,64]
        wlt[c * 256 + r] = f2bf(Wl[j]);
    } else if (i < 147456 + NNODES) {
        cnt[i - 147456] = 0;
    } else {
        int j = i - (147456 + NNODES);    // 8-elem chunk of x
        if (j < NNODES * CH / 8) {
            const float4* xp = (const float4*)(x + (size_t)j * 8);
            float4 v0 = xp[0], v1 = xp[1];
            ushort4 o0, o1;
            o0.x = f2bf(v0.x); o0.y = f2bf(v0.y); o0.z = f2bf(v0.z); o0.w = f2bf(v0.w);
            o1.x = f2bf(v1.x); o1.y = f2bf(v1.y); o1.z = f2bf(v1.z); o1.w = f2bf(v1.w);
            *(ushort4*)(xbf + (size_t)j * 8)     = o0;
            *(ushort4*)(xbf + (size_t)j * 8 + 4) = o1;
        }
    }
}

// ------- one-pass bucket-CSR: append src into fixed-stride slots of dst -------
__global__ void k_scatter(const int* __restrict__ dst, const int* __restrict__ src,
                          int* __restrict__ cnt, int* __restrict__ esrc) {
    int e = blockIdx.x * 256 + threadIdx.x;
    if (e < NEDGES) {
        int d = dst[e];
        if ((unsigned)d < NNODES) {
            int p = atomicAdd(&cnt[d], 1);
            if (p < DCAP) esrc[(size_t)d * DCAP + p] = src[e];
        }
    }
}

// ---------------- weight-stationary GEMM: full B in LDS, one barrier ----------------
// 512 threads (8 waves). All waves stage B ([BN][256] bf16, XOR-swizzled via
// pre-swizzled global src) then ONE __syncthreads. Waves 0..6 each own a 32-row
// super-tile: 16 A-loads up front (MLP), then 8x NT swizzled ds_read_b128, each
// feeding 2 MFMAs. No further barriers. HEL>0 fuses the el/er epilogue.
template<int BN, bool AF32, bool OUTF32, int HEL>
__global__ __launch_bounds__(512, 1) void k_gemmw(
        const void* __restrict__ Av, const unsigned short* __restrict__ BT,
        const float* __restrict__ bias,
        float* __restrict__ Cf, unsigned short* __restrict__ Cb,
        int M, int N,
        const float* __restrict__ al, const float* __restrict__ ar,
        float* __restrict__ el, float* __restrict__ er) {
    constexpr int NT     = BN / 16;
    constexpr int ROUNDS = (BN * 512) / 8192;     // 16 (BN=256) / 4 (BN=64)
    __shared__ unsigned short Bw[BN * 256];       // 128 KB (BN=256) / 32 KB (BN=64)
    const int t  = threadIdx.x;
    const int w  = t >> 6, l = t & 63;
    const int lm = l & 15, lg = l >> 4;

    // ---- stage all of B: linear LDS dst, inverse-swizzled global src ----
#pragma unroll
    for (int r = 0; r < ROUNDS; ++r) {
        int g   = r * 8192 + t * 16;              // linear dst byte
        int row = g >> 9;
        int bir = g & 511;
        int sb  = (g & ~511) | (bir ^ ((row & 7) << 4));
        gl_lds16((const char*)BT + sb, (char*)Bw + r * 8192 + w * 1024);
    }

    const int m0    = blockIdx.x * RB;
    const int Mb    = (m0 + RB < M) ? (m0 + RB) : M;
    const int tile0 = m0 + w * 32;
    const bool active = (w < 7) && (tile0 < Mb);

    // ---- A fragments: direct global->reg, issued before the barrier ----
    const unsigned short* Ab = (const unsigned short*)Av;
    const float*          Af = (const float*)Av;
    short8 af[2][8];
#pragma unroll
    for (int g = 0; g < 2; ++g) {
        int arow = tile0 + g * 16 + lm;
        bool ok = active && (arow < M);
#pragma unroll
        for (int ks = 0; ks < 8; ++ks) {
            if (AF32) {
                short8 v = (short8)0;
                if (ok) {
                    const float* ap = Af + (size_t)arow * 256 + ks * 32 + lg * 8;
                    float4 v0 = *(const float4*)(ap), v1 = *(const float4*)(ap + 4);
                    v[0] = (short)f2bf(v0.x); v[1] = (short)f2bf(v0.y);
                    v[2] = (short)f2bf(v0.z); v[3] = (short)f2bf(v0.w);
                    v[4] = (short)f2bf(v1.x); v[5] = (short)f2bf(v1.y);
                    v[6] = (short)f2bf(v1.z); v[7] = (short)f2bf(v1.w);
                }
                af[g][ks] = v;
            } else {
                af[g][ks] = ok ? *(const short8*)(Ab + (size_t)arow * 256 + ks * 32 + lg * 8)
                               : (short8)0;
            }
        }
    }

    __syncthreads();                              // drains gl_lds (and A loads)
    if (!active) return;

    // ---- MFMA: swizzled B reads from LDS, 2 row-groups share each fragment ----
    floatx4 acc[2][NT];
#pragma unroll
    for (int g = 0; g < 2; ++g)
#pragma unroll
        for (int nt = 0; nt < NT; ++nt) acc[g][nt] = (floatx4)0.0f;

    const int kx   = (lm >> 2) & 1;
    const int coff = (lg * 16) ^ ((lm & 3) << 4);
    const char* Bb = (const char*)Bw;
#pragma unroll
    for (int ks = 0; ks < 8; ++ks) {
        int kk = (ks ^ kx) * 64;
#pragma unroll
        for (int nt = 0; nt < NT; ++nt) {
            short8 bf = *(const short8*)(Bb + (nt * 16 + lm) * 512 + kk + coff);
            acc[0][nt] = __builtin_amdgcn_mfma_f32_16x16x32_bf16(af[0][ks], bf, acc[0][nt], 0, 0, 0);
            acc[1][nt] = __builtin_amdgcn_mfma_f32_16x16x32_bf16(af[1][ks], bf, acc[1][nt], 0, 0, 0);
        }
    }

    // ---- epilogue: C write (+ fused el/er) ----
    float alv[HEL > 0 ? NT : 1], arv[HEL > 0 ? NT : 1];
    if (HEL > 0) {
#pragma unroll
        for (int nt = 0; nt < NT; ++nt) {
            alv[nt] = al[nt * 16 + lm];
            arv[nt] = ar[nt * 16 + lm];
        }
    }
#pragma unroll
    for (int g = 0; g < 2; ++g)
#pragma unroll
        for (int j = 0; j < 4; ++j) {
            int row = tile0 + g * 16 + lg * 4 + j;
            if (row < Mb) {
#pragma unroll
                for (int nt = 0; nt < NT; ++nt) {
                    int gcol = nt * 16 + lm;
                    float v = acc[g][nt][j];
                    if (bias) v += bias[gcol];
                    if (OUTF32) Cf[(size_t)row * N + gcol] = v;
                    else        Cb[(size_t)row * N + gcol] = f2bf(v);
                }
                if (HEL > 0) {
#pragma unroll
                    for (int h = 0; h < HEL; ++h) {
                        float sl = 0.f, sr = 0.f;
#pragma unroll
                        for (int q = 0; q < NT / HEL; ++q) {
                            int nt = h * (NT / HEL) + q;
                            float v = acc[g][nt][j];
                            sl += v * alv[nt];
                            sr += v * arv[nt];
                        }
#pragma unroll
                        for (int mm = 1; mm < 16; mm <<= 1) {
                            sl += __shfl_xor(sl, mm, 64);
                            sr += __shfl_xor(sr, mm, 64);
                        }
                        if (lm == 0) {
                            el[(size_t)row * HEL + h] = sl;
                            er[(size_t)row * HEL + h] = sr;
                        }
                    }
                }
            }
        }
}

// ---------------- aggregation: inline softmax weight + scalar gather-FMA ----------------
// Bucket CSR: node n's edges at esrc[n*DCAP .. n*DCAP+deg). No LDS.
template<int H, bool ELU, bool RESID>
__global__ __launch_bounds__(256) void k_agg5(
        const unsigned short* __restrict__ ft,
        const float* __restrict__ el, const float* __restrict__ er,
        const int* __restrict__ cnt,
        const int* __restrict__ esrc,
        const unsigned short* __restrict__ resid16,
        const float* __restrict__ bias,
        unsigned short* __restrict__ out_bf,
        float* __restrict__ out_f) {
    int w = threadIdx.x >> 6;
    int n = blockIdx.x * 4 + w;
    int l = threadIdx.x & 63;
    int c = 4 * l;
    int st = n * DCAP;
    int dg = __builtin_amdgcn_readfirstlane(cnt[n]);
    if (dg > DCAP) dg = DCAP;
    if (dg < 0) dg = 0;
    float a0 = 0.f, a1 = 0.f, a2 = 0.f, a3 = 0.f, wsum = 0.f;
    const unsigned short* ftc = ft + c;

    if (H == 1) {
        float ern = er[n];
        for (int i = 0; i < dg; i += 64) {
            int idx = i + l;
            int sv = 0; float wv = 0.f;
            if (idx < dg) {
                sv = esrc[st + idx];
                float xv = el[sv] + ern;
                xv = (xv > 0.f) ? xv : 0.2f * xv;
                xv = fminf(xv, 60.f);
                wv = __expf(xv);
            }
            wsum += wv;
            int jmax = dg - i; if (jmax > 64) jmax = 64;
            int j = 0;
            for (; j + 4 <= jmax; j += 4) {
                int s0 = __builtin_amdgcn_readlane(sv, j + 0);
                int s1 = __builtin_amdgcn_readlane(sv, j + 1);
                int s2 = __builtin_amdgcn_readlane(sv, j + 2);
                int s3 = __builtin_amdgcn_readlane(sv, j + 3);
                float w0 = __int_as_float(__builtin_amdgcn_readlane(__float_as_int(wv), j + 0));
                float w1 = __int_as_float(__builtin_amdgcn_readlane(__float_as_int(wv), j + 1));
                float w2 = __int_as_float(__builtin_amdgcn_readlane(__float_as_int(wv), j + 2));
                float w3 = __int_as_float(__builtin_amdgcn_readlane(__float_as_int(wv), j + 3));
                ushort4 f0 = *(const ushort4*)(ftc + (size_t)s0 * CH);
                ushort4 f1 = *(const ushort4*)(ftc + (size_t)s1 * CH);
                ushort4 f2 = *(const ushort4*)(ftc + (size_t)s2 * CH);
                ushort4 f3 = *(const ushort4*)(ftc + (size_t)s3 * CH);
                a0 += w0 * bf2f(f0.x) + w1 * bf2f(f1.x) + w2 * bf2f(f2.x) + w3 * bf2f(f3.x);
                a1 += w0 * bf2f(f0.y) + w1 * bf2f(f1.y) + w2 * bf2f(f2.y) + w3 * bf2f(f3.y);
                a2 += w0 * bf2f(f0.z) + w1 * bf2f(f1.z) + w2 * bf2f(f2.z) + w3 * bf2f(f3.z);
                a3 += w0 * bf2f(f0.w) + w1 * bf2f(f1.w) + w2 * bf2f(f2.w) + w3 * bf2f(f3.w);
            }
            for (; j < jmax; ++j) {
                int s0 = __builtin_amdgcn_readlane(sv, j);
                float w0 = __int_as_float(__builtin_amdgcn_readlane(__float_as_int(wv), j));
                ushort4 f0 = *(const ushort4*)(ftc + (size_t)s0 * CH);
                a0 += w0 * bf2f(f0.x); a1 += w0 * bf2f(f0.y);
                a2 += w0 * bf2f(f0.z); a3 += w0 * bf2f(f0.w);
            }
        }
#pragma unroll
        for (int m = 1; m < 64; m <<= 1) wsum += __shfl_xor(wsum, m, 64);
    } else {
        int head = l & 3, slot = l >> 2;       // phase-1 role of this lane
        int h = l >> 4;                        // phase-2 head (c / 64)
        float ern = er[n * 4 + head];
        for (int i = 0; i < dg; i += 16) {
            int idx = i + slot;
            int sv = 0; float wv = 0.f;
            if (idx < dg) {
                sv = esrc[st + idx];
                float xv = el[sv * 4 + head] + ern;
                xv = (xv > 0.f) ? xv : 0.2f * xv;
                xv = fminf(xv, 60.f);
                wv = __expf(xv);
            }
            wsum += wv;
            int jmax = dg - i; if (jmax > 16) jmax = 16;
            int j = 0;
            for (; j + 4 <= jmax; j += 4) {
                int s0 = __builtin_amdgcn_readlane(sv, 4 * (j + 0));
                int s1 = __builtin_amdgcn_readlane(sv, 4 * (j + 1));
                int s2 = __builtin_amdgcn_readlane(sv, 4 * (j + 2));
                int s3 = __builtin_amdgcn_readlane(sv, 4 * (j + 3));
                float w0 = __shfl(wv, 4 * (j + 0) + h, 64);
                float w1 = __shfl(wv, 4 * (j + 1) + h, 64);
                float w2 = __shfl(wv, 4 * (j + 2) + h, 64);
                float w3 = __shfl(wv, 4 * (j + 3) + h, 64);
                ushort4 f0 = *(const ushort4*)(ftc + (size_t)s0 * CH);
                ushort4 f1 = *(const ushort4*)(ftc + (size_t)s1 * CH);
                ushort4 f2 = *(const ushort4*)(ftc + (size_t)s2 * CH);
                ushort4 f3 = *(const ushort4*)(ftc + (size_t)s3 * CH);
                a0 += w0 * bf2f(f0.x) + w1 * bf2f(f1.x) + w2 * bf2f(f2.x) + w3 * bf2f(f3.x);
                a1 += w0 * bf2f(f0.y) + w1 * bf2f(f1.y) + w2 * bf2f(f2.y) + w3 * bf2f(f3.y);
                a2 += w0 * bf2f(f0.z) + w1 * bf2f(f1.z) + w2 * bf2f(f2.z) + w3 * bf2f(f3.z);
                a3 += w0 * bf2f(f0.w) + w1 * bf2f(f1.w) + w2 * bf2f(f2.w) + w3 * bf2f(f3.w);
            }
            for (; j < jmax; ++j) {
                int s0 = __builtin_amdgcn_readlane(sv, 4 * j);
                float w0 = __shfl(wv, 4 * j + h, 64);
                ushort4 f0 = *(const ushort4*)(ftc + (size_t)s0 * CH);
                a0 += w0 * bf2f(f0.x); a1 += w0 * bf2f(f0.y);
                a2 += w0 * bf2f(f0.z); a3 += w0 * bf2f(f0.w);
            }
        }
#pragma unroll
        for (int m = 4; m < 64; m <<= 1) wsum += __shfl_xor(wsum, m, 64);
        wsum = __shfl(wsum, l >> 4, 64);
    }
    float inv = (wsum > 1e-30f) ? 1.0f / wsum : 0.0f;
    a0 *= inv; a1 *= inv; a2 *= inv; a3 *= inv;
    if (RESID) {
        ushort4 r = *(const ushort4*)(resid16 + (size_t)n * CH + c);
        a0 += bf2f(r.x); a1 += bf2f(r.y); a2 += bf2f(r.z); a3 += bf2f(r.w);
    }
    {
        float4 b = *(const float4*)(bias + c);
        a0 += b.x; a1 += b.y; a2 += b.z; a3 += b.w;
    }
    if (ELU) {
        a0 = (a0 > 0.f) ? a0 : __expf(a0) - 1.f;
        a1 = (a1 > 0.f) ? a1 : __expf(a1) - 1.f;
        a2 = (a2 > 0.f) ? a2 : __expf(a2) - 1.f;
        a3 = (a3 > 0.f) ? a3 : __expf(a3) - 1.f;
    }
    if (out_bf) {
        ushort4 ov; ov.x = f2bf(a0); ov.y = f2bf(a1); ov.z = f2bf(a2); ov.w = f2bf(a3);
        *(ushort4*)(out_bf + (size_t)n * CH + c) = ov;
    }
    if (out_f) {
        *(float4*)(out_f + (size_t)n * CH + c) = make_float4(a0, a1, a2, a3);
    }
}

// ---------------- launch ----------------

extern "C" void kernel_launch(void* const* d_in, const int* in_sizes, int n_in,
                              void* d_out, int out_size, void* d_ws, size_t ws_size,
                              hipStream_t stream) {
    const float* x   = (const float*)d_in[0];
    const int*   src = (const int*)d_in[1];
    const int*   dst = (const int*)d_in[2];
    const float* W0  = (const float*)d_in[3];
    const float* al0 = (const float*)d_in[4];
    const float* ar0 = (const float*)d_in[5];
    const float* b0  = (const float*)d_in[6];
    const float* W1  = (const float*)d_in[7];
    const float* al1 = (const float*)d_in[8];
    const float* ar1 = (const float*)d_in[9];
    const float* b1  = (const float*)d_in[10];
    const float* Wl  = (const float*)d_in[11];
    const float* bl  = (const float*)d_in[12];

    float* out_logits = (float*)d_out;
    float* out_h      = out_logits + (size_t)NNODES * NCLS;

    // xbf (25.6 MB) lives in the out_h region: dead after GEMM-0, long before agg<1> writes out_h
    unsigned short* xbf = (unsigned short*)out_h;

    // ws: ft 25.6 + h0bf 25.6 + esrc 12.8 + weights ~0.3 + small arrays (~66.5 MB total)
    char* ws = (char*)d_ws;
    size_t o = 0;
    auto alloc = [&](size_t b) { char* p = ws + o; o += (b + 255) & ~(size_t)255; return p; };
    unsigned short* ft   = (unsigned short*)alloc((size_t)NNODES * CH * 2);
    unsigned short* h0bf = (unsigned short*)alloc((size_t)NNODES * CH * 2);
    int*            esrc = (int*)alloc((size_t)NNODES * DCAP * 4);
    unsigned short* w0t  = (unsigned short*)alloc(256 * 256 * 2);
    unsigned short* w1t  = (unsigned short*)alloc(256 * 256 * 2);
    unsigned short* wlt  = (unsigned short*)alloc(64 * 256 * 2);
    int*            cnt  = (int*)alloc((size_t)NNODES * 4);
    float*          el0  = (float*)alloc((size_t)NNODES * 4 * 4);
    float*          er0  = (float*)alloc((size_t)NNODES * 4 * 4);
    float*          el1  = (float*)alloc((size_t)NNODES * 4);
    float*          er1  = (float*)alloc((size_t)NNODES * 4);

    // ---- setup (weights + xcast + cnt zero) + one-pass bucket CSR ----
    int setup_items = 147456 + NNODES + NNODES * CH / 8;
    k_setup<<<(setup_items + 255) / 256, 256, 0, stream>>>(W0, W1, Wl, x,
                                                           w0t, w1t, wlt, xbf, cnt);
    k_scatter<<<(NEDGES + 255) / 256, 256, 0, stream>>>(dst, src, cnt, esrc);

    int gm = (NNODES + RB - 1) / RB;  // 224
    // ---- layer 0 ----
    k_gemmw<256, false, false, 4><<<gm, 512, 0, stream>>>(
        xbf, w0t, nullptr, nullptr, ft, NNODES, CH, al0, ar0, el0, er0);
    k_agg5<4, true, false><<<NNODES / 4, 256, 0, stream>>>(
        ft, el0, er0, cnt, esrc, nullptr, b0, h0bf, nullptr);
    // ---- layer 1 ----
    k_gemmw<256, false, false, 1><<<gm, 512, 0, stream>>>(
        h0bf, w1t, nullptr, nullptr, ft, NNODES, CH, al1, ar1, el1, er1);
    k_agg5<1, false, true><<<NNODES / 4, 256, 0, stream>>>(
        ft, el1, er1, cnt, esrc, h0bf, b1, nullptr, out_h);
    // ---- classifier (reads out_h f32) ----
    k_gemmw<64, true, true, 0><<<gm, 512, 0, stream>>>(
        out_h, wlt, bl, out_logits, nullptr, NNODES, NCLS,
        nullptr, nullptr, nullptr, nullptr);
}